// Round 7
// baseline (976.299 us; speedup 1.0000x reference)
//
#include <hip/hip_runtime.h>

#define B_ 2
#define S_ 2048
#define HID_ 768
#define NH_ 12
#define HD_ 64
#define NSPLIT 2
#define KSPAN (S_ / NSPLIT)
#define NROWS (B_ * NH_ * S_)   // 49152 total (bh, s) rows

typedef unsigned short u16;
typedef __attribute__((ext_vector_type(8))) short bf16x8;
typedef __attribute__((ext_vector_type(4))) float f32x4;

static __device__ inline u16 f2bf(float f) {
    union { float f; unsigned u; } v; v.f = f;
    unsigned r = v.u + 0x7fffu + ((v.u >> 16) & 1u);
    return (u16)(r >> 16);
}

// ---------------- cast fp32 -> bf16, 4 elems/thread ----------------
__global__ void cast_bf16(const float* __restrict__ src, u16* __restrict__ dst, int n) {
    int i = (blockIdx.x * blockDim.x + threadIdx.x) * 4;
    if (i < n) {
        float4 v = *(const float4*)(src + i);
        unsigned lo = (unsigned)f2bf(v.x) | ((unsigned)f2bf(v.y) << 16);
        unsigned hi = (unsigned)f2bf(v.z) | ((unsigned)f2bf(v.w) << 16);
        uint2 o; o.x = lo; o.y = hi;
        *(uint2*)(dst + i) = o;
    }
}

// ---------------- QKV projection GEMM ----------------
__global__ __launch_bounds__(256) void qkv_gemm(
    const u16* __restrict__ hsb, const u16* __restrict__ wcat,
    const float* __restrict__ bq, const float* __restrict__ bk, const float* __restrict__ bv,
    u16* __restrict__ Qg, u16* __restrict__ Kg, u16* __restrict__ Vtg)
{
    __shared__ u16 As[64 * 40];
    __shared__ u16 Bs[64 * 40];
    __shared__ u16 Vs[64 * 72];

    const int m0 = blockIdx.x * 64;
    const int n0 = blockIdx.y * 64;
    const int tid = threadIdx.x;
    const int wave = tid >> 6, lane = tid & 63;
    const int l = lane & 15, quad = lane >> 4;

    f32x4 acc[4];
#pragma unroll
    for (int t = 0; t < 4; t++) acc[t] = (f32x4){0.f, 0.f, 0.f, 0.f};

    const int srow = tid >> 2;          // 0..63
    const int skg = (tid & 3) * 8;      // 0,8,16,24

    for (int k0 = 0; k0 < HID_; k0 += 32) {
        *(int4*)(&As[srow * 40 + skg]) = *(const int4*)(&hsb[(size_t)(m0 + srow) * HID_ + k0 + skg]);
        *(int4*)(&Bs[srow * 40 + skg]) = *(const int4*)(&wcat[(size_t)(n0 + srow) * HID_ + k0 + skg]);
        __syncthreads();
        bf16x8 a = *(const bf16x8*)(&As[(wave * 16 + l) * 40 + quad * 8]);
#pragma unroll
        for (int t = 0; t < 4; t++) {
            bf16x8 b = *(const bf16x8*)(&Bs[(t * 16 + l) * 40 + quad * 8]);
            acc[t] = __builtin_amdgcn_mfma_f32_16x16x32_bf16(a, b, acc[t], 0, 0, 0);
        }
        __syncthreads();
    }

    const int proj = n0 / HID_;             // 0=Q 1=K 2=V
    const int cbase = n0 - proj * HID_;     // multiple of 64
    const int h = cbase >> 6;
    const int bidx = m0 >> 11;
    const int srow0 = m0 & (S_ - 1);
    const float* bias = (proj == 0) ? bq : ((proj == 1) ? bk : bv);

    if (proj < 2) {
        u16* dst = (proj == 0) ? Qg : Kg;
        const float sc = (proj == 0) ? 0.125f : 1.0f;
#pragma unroll
        for (int t = 0; t < 4; t++) {
            const int d = t * 16 + l;
            const float bb = bias[cbase + d];
#pragma unroll
            for (int rr = 0; rr < 4; rr++) {
                int s = srow0 + wave * 16 + quad * 4 + rr;
                float v = (acc[t][rr] + bb) * sc;
                dst[(((size_t)bidx * NH_ + h) * S_ + s) * HD_ + d] = f2bf(v);
            }
        }
    } else {
        // V: transpose through LDS, write Vt[b][h][d][s] coalesced
#pragma unroll
        for (int t = 0; t < 4; t++) {
            const int d = t * 16 + l;
            const float bb = bias[cbase + d];
#pragma unroll
            for (int rr = 0; rr < 4; rr++) {
                int sl = wave * 16 + quad * 4 + rr;
                Vs[d * 72 + sl] = f2bf(acc[t][rr] + bb);
            }
        }
        __syncthreads();
        const int drow = tid >> 2;           // d 0..63
        const int sseg = (tid & 3) * 16;     // s segment
        size_t base = (((size_t)bidx * NH_ + h) * HD_ + drow) * S_ + srow0 + sseg;
        *(int4*)(&Vtg[base])     = *(const int4*)(&Vs[drow * 72 + sseg]);
        *(int4*)(&Vtg[base + 8]) = *(const int4*)(&Vs[drow * 72 + sseg + 8]);
    }
}

// ---------------- fused flash attention: 1-wave blocks, ZERO barriers ----------
// grid: (S/16, NH, B*NSPLIT), 64 threads = ONE wave owning 16 q-rows.
// No __syncthreads / s_barrier anywhere in the k-loop -> no vmcnt drain points,
// no convoying: 12-20 free-running waves/CU de-phase and keep the memory pipe
// continuously busy (rounds 0-6 all convoyed 4-wave blocks at barriers and
// pinned at 1.85-2.1 TB/s; per-block-iter wall time was ~21K cycles vs ~2K of
// compute). K/V fragments are read directly from global: K reads are dense
// 2KB chunks; K+V per (bh,split) = 256 KB, L2/L3-resident after first touch.
// P redistribution keeps the wave-private LDS path (2.3 KB, same-wave lgkm
// ordering, proven r2-r6). rel/rel2 have a 1-tile register prefetch; mask is
// loaded just-in-time (L3-hot after first head).
__global__ __launch_bounds__(64) void attn(
    const u16* __restrict__ Qg, const u16* __restrict__ Kg, const u16* __restrict__ Vtg,
    const float* __restrict__ rel, const float* __restrict__ rel2,
    const int* __restrict__ mask,
    float* __restrict__ Opart, float* __restrict__ Mpart, float* __restrict__ Lpart)
{
    __shared__ u16 Ps[16 * 72];   // wave-private P tile

    const int q0 = blockIdx.x * 16;
    const int h = blockIdx.y;
    const int b = blockIdx.z / NSPLIT;
    const int split = blockIdx.z - b * NSPLIT;
    const int lane = threadIdx.x;          // 0..63
    const int l = lane & 15, quad = lane >> 4;
    const int bh = b * NH_ + h;
    const int kbase = split * KSPAN;
    const int kend = kbase + KSPAN;

    const float NEG = -3.4028234663852886e38f;

    const u16* Kbh = Kg + (size_t)bh * S_ * HD_;
    const u16* Vbh = Vtg + (size_t)bh * HD_ * S_;

    // Q fragments (B-operand of swapped MFMA) stay in registers
    bf16x8 qf0 = *(const bf16x8*)(&Qg[((size_t)bh * S_ + q0 + l) * HD_ + quad * 8]);
    bf16x8 qf1 = *(const bf16x8*)(&Qg[((size_t)bh * S_ + q0 + l) * HD_ + 32 + quad * 8]);

    f32x4 o[4];
#pragma unroll
    for (int t = 0; t < 4; t++) o[t] = (f32x4){0.f, 0.f, 0.f, 0.f};
    float m_run = NEG, l_run = 0.f;   // lane reduces q-row q0+l

    // rel/rel2/mask staging: coalesced mapping (lane i -> row i>>2, col (i&3)*4)
    const int rsub = lane >> 2;             // 0..15
    const int rcol = (lane & 3) * 4;
    const float* relS  = rel  + (size_t)bh * S_ * S_ + (size_t)(q0 + rsub) * S_;
    const float* rel2S = rel2 + (size_t)bh * S_ * S_ + (size_t)(q0 + rsub) * S_;
    const int*   maskS = mask + (size_t)b  * S_ * S_ + (size_t)(q0 + rsub) * S_;
    const int srcLane = 4 * l + quad;       // redistribution permutation (r6-verified)

    // prologue: prefetch first tile's rel/rel2
    float4 pr1[4], pr2[4];
#pragma unroll
    for (int i = 0; i < 4; i++) {
        pr1[i] = *(const float4*)(relS + kbase + rcol + i * 16);
        pr2[i] = *(const float4*)(rel2S + kbase + rcol + i * 16);
    }

    for (int k0 = kbase; k0 < kend; k0 += 64) {
        // mask just-in-time (L3-hot; broadcast across 12 heads)
        int4 mk[4];
#pragma unroll
        for (int i = 0; i < 4; i++)
            mk[i] = *(const int4*)(maskS + k0 + rcol + i * 16);

        // masked sums in stager layout (mask pre-folded: adding |qk|<=1e4 to
        // -3.4e38 is below the ulp -> bit-identical to post-MFMA masking)
        f32x4 ss[4];
#pragma unroll
        for (int i = 0; i < 4; i++) {
            ss[i][0] = mk[i].x ? NEG : pr1[i].x + pr2[i].x;
            ss[i][1] = mk[i].y ? NEG : pr1[i].y + pr2[i].y;
            ss[i][2] = mk[i].z ? NEG : pr1[i].z + pr2[i].z;
            ss[i][3] = mk[i].w ? NEG : pr1[i].w + pr2[i].w;
        }

        // prefetch next tile's rel/rel2 (no barriers anywhere -> these stay in
        // flight under the whole MFMA/softmax/PV phase, counted vmcnt only)
        if (k0 + 64 < kend) {
#pragma unroll
            for (int i = 0; i < 4; i++) {
                pr1[i] = *(const float4*)(relS + k0 + 64 + rcol + i * 16);
                pr2[i] = *(const float4*)(rel2S + k0 + 64 + rcol + i * 16);
            }
        }

        // redistribute to MFMA layout: sacc[t] = ss[t] of lane 4l+quad
        f32x4 sacc[4];
#pragma unroll
        for (int t = 0; t < 4; t++) {
            sacc[t][0] = __shfl(ss[t][0], srcLane, 64);
            sacc[t][1] = __shfl(ss[t][1], srcLane, 64);
            sacc[t][2] = __shfl(ss[t][2], srcLane, 64);
            sacc[t][3] = __shfl(ss[t][3], srcLane, 64);
        }

        // swapped QK^T; K fragments straight from global (L2-resident, dense)
#pragma unroll
        for (int t = 0; t < 4; t++) {
            bf16x8 b0 = *(const bf16x8*)(&Kbh[(size_t)(k0 + t * 16 + l) * HD_ + quad * 8]);
            sacc[t] = __builtin_amdgcn_mfma_f32_16x16x32_bf16(b0, qf0, sacc[t], 0, 0, 0);
            bf16x8 b1 = *(const bf16x8*)(&Kbh[(size_t)(k0 + t * 16 + l) * HD_ + 32 + quad * 8]);
            sacc[t] = __builtin_amdgcn_mfma_f32_16x16x32_bf16(b1, qf1, sacc[t], 0, 0, 0);
        }

        // online softmax (lanes {l,l+16,l+32,l+48} share q-row q0+l)
        float mx = NEG;
#pragma unroll
        for (int t = 0; t < 4; t++)
#pragma unroll
            for (int rr = 0; rr < 4; rr++) mx = fmaxf(mx, sacc[t][rr]);
        mx = fmaxf(mx, __shfl_xor(mx, 16, 64));
        mx = fmaxf(mx, __shfl_xor(mx, 32, 64));
        float mnew = fmaxf(m_run, mx);
        float alpha = __expf(m_run - mnew);
        float rs = 0.f;
#pragma unroll
        for (int t = 0; t < 4; t++)
#pragma unroll
            for (int rr = 0; rr < 4; rr++) {
                float p = __expf(sacc[t][rr] - mnew);
                sacc[t][rr] = p;
                rs += p;
            }
        rs += __shfl_xor(rs, 16, 64);
        rs += __shfl_xor(rs, 32, 64);
        l_run = l_run * alpha + rs;
        m_run = mnew;

        float av[4];
#pragma unroll
        for (int rr = 0; rr < 4; rr++) av[rr] = __shfl(alpha, quad * 4 + rr, 64);
#pragma unroll
        for (int dt = 0; dt < 4; dt++)
#pragma unroll
            for (int rr = 0; rr < 4; rr++) o[dt][rr] *= av[rr];

        // P -> wave-private LDS (same-wave ds ordering; compiler lgkmcnt)
#pragma unroll
        for (int t = 0; t < 4; t++) {
            unsigned p01 = (unsigned)f2bf(sacc[t][0]) | ((unsigned)f2bf(sacc[t][1]) << 16);
            unsigned p23 = (unsigned)f2bf(sacc[t][2]) | ((unsigned)f2bf(sacc[t][3]) << 16);
            uint2 pw; pw.x = p01; pw.y = p23;
            *(uint2*)(&Ps[l * 72 + t * 16 + quad * 4]) = pw;
        }

        // PV: O += P * V; V^T fragments straight from global (L2-resident)
        bf16x8 pa0 = *(const bf16x8*)(&Ps[l * 72 + quad * 8]);
        bf16x8 pa1 = *(const bf16x8*)(&Ps[l * 72 + 32 + quad * 8]);
#pragma unroll
        for (int dt = 0; dt < 4; dt++) {
            bf16x8 v0 = *(const bf16x8*)(&Vbh[(size_t)(dt * 16 + l) * S_ + k0 + quad * 8]);
            o[dt] = __builtin_amdgcn_mfma_f32_16x16x32_bf16(pa0, v0, o[dt], 0, 0, 0);
            bf16x8 v1 = *(const bf16x8*)(&Vbh[(size_t)(dt * 16 + l) * S_ + k0 + 32 + quad * 8]);
            o[dt] = __builtin_amdgcn_mfma_f32_16x16x32_bf16(pa1, v1, o[dt], 0, 0, 0);
        }
    }

    // epilogue: unnormalized partial O + per-row (m, l) for this split
    float* Op = Opart + (((size_t)split * B_ * NH_ + bh) * S_ + q0) * HD_;
#pragma unroll
    for (int dt = 0; dt < 4; dt++) {
#pragma unroll
        for (int rr = 0; rr < 4; rr++) {
            const int row = quad * 4 + rr;
            Op[(size_t)row * HD_ + dt * 16 + l] = o[dt][rr];
        }
    }
    if (quad == 0) {
        const size_t mi = ((size_t)split * B_ * NH_ + bh) * S_ + q0 + l;
        Mpart[mi] = m_run;
        Lpart[mi] = l_run;
    }
}

// ---------------- split-K combine ----------------
__global__ __launch_bounds__(256) void combine(
    const float* __restrict__ Op, const float* __restrict__ Mp, const float* __restrict__ Lp,
    float* __restrict__ out)
{
    const int idx = blockIdx.x * 256 + threadIdx.x;   // NROWS*16 total
    const int r = idx >> 4;            // bh*S + s
    const int dseg = (idx & 15) * 4;
    const float m0 = Mp[r], m1 = Mp[NROWS + r];
    const float l0 = Lp[r], l1 = Lp[NROWS + r];
    const float m = fmaxf(m0, m1);
    const float a0 = __expf(m0 - m), a1 = __expf(m1 - m);
    const float inv = 1.0f / (l0 * a0 + l1 * a1);
    const float4 o0 = *(const float4*)(Op + (size_t)r * HD_ + dseg);
    const float4 o1 = *(const float4*)(Op + ((size_t)NROWS + r) * HD_ + dseg);
    float4 res;
    res.x = (o0.x * a0 + o1.x * a1) * inv;
    res.y = (o0.y * a0 + o1.y * a1) * inv;
    res.z = (o0.z * a0 + o1.z * a1) * inv;
    res.w = (o0.w * a0 + o1.w * a1) * inv;
    const int bh_ = r >> 11;                // r / S_
    const int s = r & (S_ - 1);
    const int b = bh_ / NH_;
    const int h = bh_ - b * NH_;
    *(float4*)(out + ((size_t)(b * S_ + s)) * HID_ + h * HD_ + dseg) = res;
}

extern "C" void kernel_launch(void* const* d_in, const int* in_sizes, int n_in,
                              void* d_out, int out_size, void* d_ws, size_t ws_size,
                              hipStream_t stream) {
    const float* hs   = (const float*)d_in[0];
    const float* rel  = (const float*)d_in[1];
    const float* rel2 = (const float*)d_in[2];
    const int*   mask = (const int*)d_in[3];
    const float* Wq = (const float*)d_in[4];
    const float* bq = (const float*)d_in[5];
    const float* Wk = (const float*)d_in[6];
    const float* bk = (const float*)d_in[7];
    const float* Wv = (const float*)d_in[8];
    const float* bv = (const float*)d_in[9];
    float* out = (float*)d_out;

    char* ws = (char*)d_ws;
    u16* hsb   = (u16*)(ws);                      // 4096*768 bf16   = 6291456 B
    u16* wcat  = (u16*)(ws + 6291456);            // 2304*768 bf16   = 3538944 B
    u16* Qg    = (u16*)(ws + 9830400);            // [B][NH][S][HD]  = 6291456 B
    u16* Kg    = (u16*)(ws + 16121856);           // same
    u16* Vtg   = (u16*)(ws + 22413312);           // [B][NH][HD][S]  = 6291456 B
    float* Opart = (float*)(ws + 28704768);       // [2][B][NH][S][HD] f32 = 25165824 B
    float* Mpart = (float*)(ws + 53870592);       // [2][B*NH*S] f32 = 393216 B
    float* Lpart = (float*)(ws + 54263808);       // [2][B*NH*S] f32 = 393216 B

    // casts
    cast_bf16<<<3072, 256, 0, stream>>>(hs, hsb, B_ * S_ * HID_);
    cast_bf16<<<576, 256, 0, stream>>>(Wq, wcat,             HID_ * HID_);
    cast_bf16<<<576, 256, 0, stream>>>(Wk, wcat + HID_ * HID_,     HID_ * HID_);
    cast_bf16<<<576, 256, 0, stream>>>(Wv, wcat + 2 * HID_ * HID_, HID_ * HID_);

    // QKV projections
    qkv_gemm<<<dim3(64, 36), 256, 0, stream>>>(hsb, wcat, bq, bk, bv, Qg, Kg, Vtg);

    // fused attention: 1-wave barrier-free blocks, 2-way split-K
    attn<<<dim3(S_ / 16, NH_, B_ * NSPLIT), 64, 0, stream>>>(
        Qg, Kg, Vtg, rel, rel2, mask, Opart, Mpart, Lpart);

    // merge halves
    combine<<<(NROWS * 16) / 256, 256, 0, stream>>>(Opart, Mpart, Lpart, out);
}

// Round 8
// 931.636 us; speedup vs baseline: 1.0479x; 1.0479x over previous
//
#include <hip/hip_runtime.h>

#define B_ 2
#define S_ 2048
#define HID_ 768
#define NH_ 12
#define HD_ 64
#define NSPLIT 2
#define KSPAN (S_ / NSPLIT)
#define NROWS (B_ * NH_ * S_)   // 49152 total (bh, s) rows

typedef unsigned short u16;
typedef unsigned int uint;
typedef __attribute__((ext_vector_type(8))) short bf16x8;
typedef __attribute__((ext_vector_type(4))) float f32x4;

static __device__ inline u16 f2bf(float f) {
    union { float f; unsigned u; } v; v.f = f;
    unsigned r = v.u + 0x7fffu + ((v.u >> 16) & 1u);
    return (u16)(r >> 16);
}
static __device__ inline float bf2f(uint u) {
    union { unsigned u; float f; } v; v.u = u << 16; return v.f;
}

// LDS-only barrier: waits ds ops, leaves vmcnt (global loads) IN FLIGHT.
#define LDS_BARRIER() asm volatile("s_waitcnt lgkmcnt(0)\n\ts_barrier" ::: "memory")

// ---------------- cast fp32 -> bf16, 4 elems/thread ----------------
__global__ void cast_bf16(const float* __restrict__ src, u16* __restrict__ dst, int n) {
    int i = (blockIdx.x * blockDim.x + threadIdx.x) * 4;
    if (i < n) {
        float4 v = *(const float4*)(src + i);
        unsigned lo = (unsigned)f2bf(v.x) | ((unsigned)f2bf(v.y) << 16);
        unsigned hi = (unsigned)f2bf(v.z) | ((unsigned)f2bf(v.w) << 16);
        uint2 o; o.x = lo; o.y = hi;
        *(uint2*)(dst + i) = o;
    }
}

// ---------------- bit-pack attention mask: 64 int32 -> uint2 per wave --------
// Cuts per-dispatch mask demand from 402 MB (33.5 MB x 12 heads) to 13 MB.
__global__ __launch_bounds__(256) void pack_mask(const int* __restrict__ m, uint2* __restrict__ out) {
    const int w = blockIdx.x * 4 + (threadIdx.x >> 6);   // word index
    const int lane = threadIdx.x & 63;
    const int v = m[(size_t)w * 64 + lane];
    unsigned long long bl = __ballot(v != 0);
    if (lane == 0) { uint2 o; o.x = (uint)bl; o.y = (uint)(bl >> 32); out[w] = o; }
}

// ---------------- QKV projection GEMM ----------------
__global__ __launch_bounds__(256) void qkv_gemm(
    const u16* __restrict__ hsb, const u16* __restrict__ wcat,
    const float* __restrict__ bq, const float* __restrict__ bk, const float* __restrict__ bv,
    u16* __restrict__ Qg, u16* __restrict__ Kg, u16* __restrict__ Vtg)
{
    __shared__ u16 As[64 * 40];
    __shared__ u16 Bs[64 * 40];
    __shared__ u16 Vs[64 * 72];

    const int m0 = blockIdx.x * 64;
    const int n0 = blockIdx.y * 64;
    const int tid = threadIdx.x;
    const int wave = tid >> 6, lane = tid & 63;
    const int l = lane & 15, quad = lane >> 4;

    f32x4 acc[4];
#pragma unroll
    for (int t = 0; t < 4; t++) acc[t] = (f32x4){0.f, 0.f, 0.f, 0.f};

    const int srow = tid >> 2;          // 0..63
    const int skg = (tid & 3) * 8;      // 0,8,16,24

    for (int k0 = 0; k0 < HID_; k0 += 32) {
        *(int4*)(&As[srow * 40 + skg]) = *(const int4*)(&hsb[(size_t)(m0 + srow) * HID_ + k0 + skg]);
        *(int4*)(&Bs[srow * 40 + skg]) = *(const int4*)(&wcat[(size_t)(n0 + srow) * HID_ + k0 + skg]);
        __syncthreads();
        bf16x8 a = *(const bf16x8*)(&As[(wave * 16 + l) * 40 + quad * 8]);
#pragma unroll
        for (int t = 0; t < 4; t++) {
            bf16x8 b = *(const bf16x8*)(&Bs[(t * 16 + l) * 40 + quad * 8]);
            acc[t] = __builtin_amdgcn_mfma_f32_16x16x32_bf16(a, b, acc[t], 0, 0, 0);
        }
        __syncthreads();
    }

    const int proj = n0 / HID_;             // 0=Q 1=K 2=V
    const int cbase = n0 - proj * HID_;     // multiple of 64
    const int h = cbase >> 6;
    const int bidx = m0 >> 11;
    const int srow0 = m0 & (S_ - 1);
    const float* bias = (proj == 0) ? bq : ((proj == 1) ? bk : bv);

    if (proj < 2) {
        u16* dst = (proj == 0) ? Qg : Kg;
        const float sc = (proj == 0) ? 0.125f : 1.0f;
#pragma unroll
        for (int t = 0; t < 4; t++) {
            const int d = t * 16 + l;
            const float bb = bias[cbase + d];
#pragma unroll
            for (int rr = 0; rr < 4; rr++) {
                int s = srow0 + wave * 16 + quad * 4 + rr;
                float v = (acc[t][rr] + bb) * sc;
                dst[(((size_t)bidx * NH_ + h) * S_ + s) * HD_ + d] = f2bf(v);
            }
        }
    } else {
        // V: transpose through LDS, write Vt[b][h][d][s] coalesced
#pragma unroll
        for (int t = 0; t < 4; t++) {
            const int d = t * 16 + l;
            const float bb = bias[cbase + d];
#pragma unroll
            for (int rr = 0; rr < 4; rr++) {
                int sl = wave * 16 + quad * 4 + rr;
                Vs[d * 72 + sl] = f2bf(acc[t][rr] + bb);
            }
        }
        __syncthreads();
        const int drow = tid >> 2;           // d 0..63
        const int sseg = (tid & 3) * 16;     // s segment
        size_t base = (((size_t)bidx * NH_ + h) * HD_ + drow) * S_ + srow0 + sseg;
        *(int4*)(&Vtg[base])     = *(const int4*)(&Vs[drow * 72 + sseg]);
        *(int4*)(&Vtg[base + 8]) = *(const int4*)(&Vs[drow * 72 + sseg + 8]);
    }
}

// ---------------- fused flash attention: 1 KB-burst superstep staging ---------
// grid: (S/64, NH, B*NSPLIT), 256 threads = 4 waves, 2-way split-K.
// Superstep = 4 k-tiles (256 cols). Each wave stages its 16 q-rows' rel+rel2
// with WHOLE-WAVE row reads: 64 lanes x float4 = 1 KB contiguous per load
// (vs 256 B granules in r0-r7 -> DRAM page-activate-bound at ~2 TB/s).
// Sum + bitpacked-mask fold happen in-register; result stored as bf16 relsum
// in wave-private LDS [64][268]. Score init = 4x ds_read_b64. P->PV transport
// via 16 shfl (Ps LDS buffer deleted) -> 52.7 KB LDS -> 3 blocks/CU.
__global__ __launch_bounds__(256) void attn(
    const u16* __restrict__ Qg, const u16* __restrict__ Kg, const u16* __restrict__ Vtg,
    const float* __restrict__ rel, const float* __restrict__ rel2,
    const uint2* __restrict__ maskb,
    float* __restrict__ Opart, float* __restrict__ Mpart, float* __restrict__ Lpart)
{
    __shared__ u16 relsum[64 * 268];   // bf16 rel+rel2(+mask), superstep-local cols
    __shared__ u16 Ks[64 * 72];
    __shared__ u16 Vts[64 * 72];

    const int q0 = blockIdx.x * 64;
    const int h = blockIdx.y;
    const int b = blockIdx.z / NSPLIT;
    const int split = blockIdx.z - b * NSPLIT;
    const int tid = threadIdx.x;
    const int wave = tid >> 6, lane = tid & 63;
    const int l = lane & 15, quad = lane >> 4;
    const int bh = b * NH_ + h;
    const int kbase = split * KSPAN;

    const float NEG = -3.4028234663852886e38f;

    // Q fragments (B-operand of swapped MFMA) stay in registers
    bf16x8 qf0, qf1;
    {
        const int qr = q0 + wave * 16 + l;
        qf0 = *(const bf16x8*)(&Qg[((size_t)bh * S_ + qr) * HD_ + quad * 8]);
        qf1 = *(const bf16x8*)(&Qg[((size_t)bh * S_ + qr) * HD_ + 32 + quad * 8]);
    }

    f32x4 o[4];
#pragma unroll
    for (int t = 0; t < 4; t++) o[t] = (f32x4){0.f, 0.f, 0.f, 0.f};
    float m_run = NEG, l_run = 0.f;   // lane reduces q-row q0+wave*16+l

    const int srow = tid >> 2;        // K/V staging row 0..63 (block-wide)
    const int sseg = (tid & 3) * 8;   // 0,8,16,24

    const float* relQ  = rel  + (size_t)bh * S_ * S_ + (size_t)q0 * S_;
    const float* rel2Q = rel2 + (size_t)bh * S_ * S_ + (size_t)q0 * S_;
    const uint2* mQ    = maskb + (size_t)(b * S_ + q0) * (S_ / 64);

    const int A16a = l + 32 * (quad & 1);       // P-shuffle source lanes
    const int A16b = A16a + 16;

    for (int ss = 0; ss < KSPAN; ss += 256) {
        const int c0 = kbase + ss;

        // ---- STAGE relsum: this wave's 16 rows, 1 KB contiguous per load ----
#pragma unroll
        for (int g = 0; g < 2; g++) {
            float4 xa[8], xb[8];
            uint2  xm[8];
#pragma unroll
            for (int r = 0; r < 8; r++) {
                const int rowl = wave * 16 + g * 8 + r;
                xa[r] = *(const float4*)(relQ  + (size_t)rowl * S_ + c0 + 4 * lane);
                xb[r] = *(const float4*)(rel2Q + (size_t)rowl * S_ + c0 + 4 * lane);
                xm[r] = mQ[(size_t)rowl * (S_ / 64) + (c0 >> 6) + (lane >> 4)];
            }
#pragma unroll
            for (int r = 0; r < 8; r++) {
                const int rowl = wave * 16 + g * 8 + r;
                const uint wsel = (lane & 8) ? xm[r].y : xm[r].x;
                const uint nib = (wsel >> ((lane & 7) * 4)) & 0xF;
                const u16 NEGB = (u16)0xFF7F;   // bf16 -3.3895e38
                u16 e0 = (nib & 1) ? NEGB : f2bf(xa[r].x + xb[r].x);
                u16 e1 = (nib & 2) ? NEGB : f2bf(xa[r].y + xb[r].y);
                u16 e2 = (nib & 4) ? NEGB : f2bf(xa[r].z + xb[r].z);
                u16 e3 = (nib & 8) ? NEGB : f2bf(xa[r].w + xb[r].w);
                uint2 pw; pw.x = (uint)e0 | ((uint)e1 << 16); pw.y = (uint)e2 | ((uint)e3 << 16);
                *(uint2*)(&relsum[rowl * 268 + 4 * lane]) = pw;
            }
        }

        // ---- 4 inner k-tiles from LDS/L2 ----
#pragma unroll
        for (int t = 0; t < 4; t++) {
            const int k0 = c0 + t * 64;

            // stage K/V (block-wide, L2-resident source)
            size_t kg = ((size_t)bh * S_ + k0 + srow) * HD_;
            int4 ka = *(const int4*)(&Kg[kg + sseg]);
            int4 kb = *(const int4*)(&Kg[kg + 32 + sseg]);
            size_t vg = ((size_t)bh * HD_ + srow) * S_ + k0;
            int4 va = *(const int4*)(&Vtg[vg + sseg]);
            int4 vb = *(const int4*)(&Vtg[vg + 32 + sseg]);
            *(int4*)(&Ks[srow * 72 + sseg])       = ka;
            *(int4*)(&Ks[srow * 72 + 32 + sseg])  = kb;
            *(int4*)(&Vts[srow * 72 + sseg])      = va;
            *(int4*)(&Vts[srow * 72 + 32 + sseg]) = vb;
            LDS_BARRIER();

            // score init from relsum (wave-private rows; superstep-local cols)
            f32x4 sacc[4];
#pragma unroll
            for (int tt = 0; tt < 4; tt++) {
                uint2 rv = *(const uint2*)(&relsum[(wave * 16 + l) * 268 + ss - ss /*local*/ + t * 64 + tt * 16 + quad * 4]);
                sacc[tt][0] = bf2f(rv.x & 0xFFFFu);
                sacc[tt][1] = bf2f(rv.x >> 16);
                sacc[tt][2] = bf2f(rv.y & 0xFFFFu);
                sacc[tt][3] = bf2f(rv.y >> 16);
            }

            // swapped QK^T: sacc[tt][rr] = scores[qrow][k0 + tt*16 + quad*4 + rr]
#pragma unroll
            for (int tt = 0; tt < 4; tt++) {
                bf16x8 b0 = *(const bf16x8*)(&Ks[(tt * 16 + l) * 72 + quad * 8]);
                sacc[tt] = __builtin_amdgcn_mfma_f32_16x16x32_bf16(b0, qf0, sacc[tt], 0, 0, 0);
                bf16x8 b1 = *(const bf16x8*)(&Ks[(tt * 16 + l) * 72 + 32 + quad * 8]);
                sacc[tt] = __builtin_amdgcn_mfma_f32_16x16x32_bf16(b1, qf1, sacc[tt], 0, 0, 0);
            }

            // online softmax (lanes {l,l+16,l+32,l+48} share a q-row)
            float mx = NEG;
#pragma unroll
            for (int tt = 0; tt < 4; tt++)
#pragma unroll
                for (int rr = 0; rr < 4; rr++) mx = fmaxf(mx, sacc[tt][rr]);
            mx = fmaxf(mx, __shfl_xor(mx, 16, 64));
            mx = fmaxf(mx, __shfl_xor(mx, 32, 64));
            float mnew = fmaxf(m_run, mx);
            float alpha = __expf(m_run - mnew);
            float rs = 0.f;
#pragma unroll
            for (int tt = 0; tt < 4; tt++)
#pragma unroll
                for (int rr = 0; rr < 4; rr++) {
                    float p = __expf(sacc[tt][rr] - mnew);
                    sacc[tt][rr] = p;
                    rs += p;
                }
            rs += __shfl_xor(rs, 16, 64);
            rs += __shfl_xor(rs, 32, 64);
            l_run = l_run * alpha + rs;
            m_run = mnew;

            float av[4];
#pragma unroll
            for (int rr = 0; rr < 4; rr++) av[rr] = __shfl(alpha, quad * 4 + rr, 64);
#pragma unroll
            for (int dt = 0; dt < 4; dt++)
#pragma unroll
                for (int rr = 0; rr < 4; rr++) o[dt][rr] *= av[rr];

            // P -> PV A-fragments via shuffles (no LDS).
            // pk0[tt]=P[l][16tt+4q+{0,1}], pk1[tt]=+{2,3}; dest (l,q) ks-half needs
            // t=2ks+(q>>1) from lanes A16a/A16b, selected by (q&2) after shuffle.
            uint pk0[4], pk1[4];
#pragma unroll
            for (int tt = 0; tt < 4; tt++) {
                pk0[tt] = (uint)f2bf(sacc[tt][0]) | ((uint)f2bf(sacc[tt][1]) << 16);
                pk1[tt] = (uint)f2bf(sacc[tt][2]) | ((uint)f2bf(sacc[tt][3]) << 16);
            }
            bf16x8 pa[2];
#pragma unroll
            for (int ks = 0; ks < 2; ks++) {
                uint a0 = (uint)__shfl((int)pk0[2 * ks],     A16a, 64);
                uint b0 = (uint)__shfl((int)pk0[2 * ks + 1], A16a, 64);
                uint a1 = (uint)__shfl((int)pk1[2 * ks],     A16a, 64);
                uint b1 = (uint)__shfl((int)pk1[2 * ks + 1], A16a, 64);
                uint a2 = (uint)__shfl((int)pk0[2 * ks],     A16b, 64);
                uint b2 = (uint)__shfl((int)pk0[2 * ks + 1], A16b, 64);
                uint a3 = (uint)__shfl((int)pk1[2 * ks],     A16b, 64);
                uint b3 = (uint)__shfl((int)pk1[2 * ks + 1], A16b, 64);
                const bool hi = (quad & 2);
                union { uint u[4]; bf16x8 v; } cv;
                cv.u[0] = hi ? b0 : a0;
                cv.u[1] = hi ? b1 : a1;
                cv.u[2] = hi ? b2 : a2;
                cv.u[3] = hi ? b3 : a3;
                pa[ks] = cv.v;
            }

            // PV: O += P * V
#pragma unroll
            for (int dt = 0; dt < 4; dt++) {
                bf16x8 v0 = *(const bf16x8*)(&Vts[(dt * 16 + l) * 72 + quad * 8]);
                o[dt] = __builtin_amdgcn_mfma_f32_16x16x32_bf16(pa[0], v0, o[dt], 0, 0, 0);
                bf16x8 v1 = *(const bf16x8*)(&Vts[(dt * 16 + l) * 72 + 32 + quad * 8]);
                o[dt] = __builtin_amdgcn_mfma_f32_16x16x32_bf16(pa[1], v1, o[dt], 0, 0, 0);
            }
            LDS_BARRIER();   // K/V reads done before next tile's staging
        }
    }

    // epilogue: unnormalized partial O + per-row (m, l) for this split
    float* Op = Opart + (((size_t)split * B_ * NH_ + bh) * S_ + q0) * HD_;
#pragma unroll
    for (int dt = 0; dt < 4; dt++) {
#pragma unroll
        for (int rr = 0; rr < 4; rr++) {
            const int row = wave * 16 + quad * 4 + rr;
            Op[(size_t)row * HD_ + dt * 16 + l] = o[dt][rr];
        }
    }
    if (quad == 0) {
        const size_t mi = ((size_t)split * B_ * NH_ + bh) * S_ + q0 + wave * 16 + l;
        Mpart[mi] = m_run;
        Lpart[mi] = l_run;
    }
}

// ---------------- split-K combine ----------------
__global__ __launch_bounds__(256) void combine(
    const float* __restrict__ Op, const float* __restrict__ Mp, const float* __restrict__ Lp,
    float* __restrict__ out)
{
    const int idx = blockIdx.x * 256 + threadIdx.x;   // NROWS*16 total
    const int r = idx >> 4;            // bh*S + s
    const int dseg = (idx & 15) * 4;
    const float m0 = Mp[r], m1 = Mp[NROWS + r];
    const float l0 = Lp[r], l1 = Lp[NROWS + r];
    const float m = fmaxf(m0, m1);
    const float a0 = __expf(m0 - m), a1 = __expf(m1 - m);
    const float inv = 1.0f / (l0 * a0 + l1 * a1);
    const float4 o0 = *(const float4*)(Op + (size_t)r * HD_ + dseg);
    const float4 o1 = *(const float4*)(Op + ((size_t)NROWS + r) * HD_ + dseg);
    float4 res;
    res.x = (o0.x * a0 + o1.x * a1) * inv;
    res.y = (o0.y * a0 + o1.y * a1) * inv;
    res.z = (o0.z * a0 + o1.z * a1) * inv;
    res.w = (o0.w * a0 + o1.w * a1) * inv;
    const int bh_ = r >> 11;                // r / S_
    const int s = r & (S_ - 1);
    const int b = bh_ / NH_;
    const int h = bh_ - b * NH_;
    *(float4*)(out + ((size_t)(b * S_ + s)) * HID_ + h * HD_ + dseg) = res;
}

extern "C" void kernel_launch(void* const* d_in, const int* in_sizes, int n_in,
                              void* d_out, int out_size, void* d_ws, size_t ws_size,
                              hipStream_t stream) {
    const float* hs   = (const float*)d_in[0];
    const float* rel  = (const float*)d_in[1];
    const float* rel2 = (const float*)d_in[2];
    const int*   mask = (const int*)d_in[3];
    const float* Wq = (const float*)d_in[4];
    const float* bq = (const float*)d_in[5];
    const float* Wk = (const float*)d_in[6];
    const float* bk = (const float*)d_in[7];
    const float* Wv = (const float*)d_in[8];
    const float* bv = (const float*)d_in[9];
    float* out = (float*)d_out;

    char* ws = (char*)d_ws;
    u16* hsb   = (u16*)(ws);                      // 4096*768 bf16   = 6291456 B
    u16* wcat  = (u16*)(ws + 6291456);            // 2304*768 bf16   = 3538944 B
    u16* Qg    = (u16*)(ws + 9830400);            // [B][NH][S][HD]  = 6291456 B
    u16* Kg    = (u16*)(ws + 16121856);           // same
    u16* Vtg   = (u16*)(ws + 22413312);           // [B][NH][HD][S]  = 6291456 B
    float* Opart = (float*)(ws + 28704768);       // [2][B][NH][S][HD] f32 = 25165824 B
    float* Mpart = (float*)(ws + 53870592);       // [2][B*NH*S] f32 = 393216 B
    float* Lpart = (float*)(ws + 54263808);       // [2][B*NH*S] f32 = 393216 B
    uint2* maskb = (uint2*)(ws + 54657024);       // [B][S][S/64] bitmask = 1048576 B

    // casts + mask bit-pack
    cast_bf16<<<3072, 256, 0, stream>>>(hs, hsb, B_ * S_ * HID_);
    cast_bf16<<<576, 256, 0, stream>>>(Wq, wcat,             HID_ * HID_);
    cast_bf16<<<576, 256, 0, stream>>>(Wk, wcat + HID_ * HID_,     HID_ * HID_);
    cast_bf16<<<576, 256, 0, stream>>>(Wv, wcat + 2 * HID_ * HID_, HID_ * HID_);
    pack_mask<<<(B_ * S_ * S_ / 64) / 4, 256, 0, stream>>>(mask, maskb);

    // QKV projections
    qkv_gemm<<<dim3(64, 36), 256, 0, stream>>>(hsb, wcat, bq, bk, bv, Qg, Kg, Vtg);

    // fused attention: superstep-staged, 2-way split-K
    attn<<<dim3(S_ / 64, NH_, B_ * NSPLIT), 256, 0, stream>>>(
        Qg, Kg, Vtg, rel, rel2, maskb, Opart, Mpart, Lpart);

    // merge halves
    combine<<<(NROWS * 16) / 256, 256, 0, stream>>>(Opart, Mpart, Lpart, out);
}